// Round 10
// baseline (39051.804 us; speedup 1.0000x reference)
//
#include <hip/hip_runtime.h>
#include <cstdint>
#include <cstddef>

// Problem constants (match reference)
#define B_    64
#define C_    128
#define T_    500
#define NRES  2048
#define NCLS  10

// Kernel org: one thread per (batch, neuron) element; wg w owns neurons [8w, 8w+8)
#define NWG   256          // one workgroup per CU (forced by LDS pad)
#define SL    8            // neurons per wg
#define NT    512          // threads: tid = il*64 + b  (wave = one neuron il, lanes = batches)

// AOCL/BLIS K-blocking hypothesis: no tail-halving, KC=512 (zen sgemm)
// => K=2048 splits as [512,512,512,512]; fold boundaries at k=512,1024,1536
// => mask words {16, 32, 48}
#define FOLDMASK ((1ull<<16)|(1ull<<32)|(1ull<<48))

// d_ws layout: [0,16384) mask buf0, [16384,32768) mask buf1, [32768,+4) barrier counter
#define WS_MASK0   0
#define WS_MASK1   16384
#define WS_CNT     32768
#define WS_WORDS   8256

struct SMem {
  float    xs[B_][C_ + 1];          // 33024 B : x[:, :, t], row-padded
  unsigned mask[B_][65];            // 16640 B : spike bits s(t-1), row-padded
  unsigned long long balls[SL];     //    64 B : per-wave spike ballots
  double   clfred[8][NCLS];         //   640 B : classifier per-wave partials (f64)
  char     pad[32768];              // pad: total 83136 B > 80 KiB => 1 wg/CU forced
};

__global__ void zero_ws_kernel(unsigned* __restrict__ p, int n) {
  int i = blockIdx.x * blockDim.x + threadIdx.x;
  if (i < n) p[i] = 0u;
}

__global__ void __launch_bounds__(NT, 1)
reservoir_kernel(const float* __restrict__ x, const float* __restrict__ Win,
                 const float* __restrict__ Wres, const float* __restrict__ Wclf,
                 float* __restrict__ out, unsigned char* __restrict__ ws) {
  __shared__ SMem sm;
  const int w   = blockIdx.x;
  const int tid = threadIdx.x;
  const int b   = tid & 63;        // lane = batch
  const int il  = tid >> 6;        // wave = local neuron index
  // wave-uniform global neuron id -> W rows come in via SGPR s_loads
  const int iu  = __builtin_amdgcn_readfirstlane(w * SL + il);
  const float* __restrict__ wres_row = Wres + (size_t)iu * NRES;
  const float* __restrict__ win_row  = Win  + (size_t)iu * C_;

  unsigned* mbuf0 = (unsigned*)(ws + WS_MASK0);
  unsigned* mbuf1 = (unsigned*)(ws + WS_MASK1);
  unsigned* cnt   = (unsigned*)(ws + WS_CNT);

  // persistent state: replicate np f32 trajectory under the
  // AOCL/BLIS chain model (fma k-sequential, KC=512, no halving)
  float v = 0.f;                   // reservoir membrane (f32, rn ops only)
  int   cntr = 0;
  double vc = 0.0;                 // classifier membrane (no feedback -> f64 ok)
  int   cntc = 0;

  // prefetch x(:,:,0): flat pair p = tid*16 + r, p = b*C_ + c
  float xv[16];
  {
    const int p0 = tid * 16;
    #pragma unroll
    for (int r = 0; r < 16; ++r) xv[r] = x[(size_t)(p0 + r) * T_ + 0];
  }

  for (int t = 0; t < T_; ++t) {
    unsigned* prevm = (t & 1) ? mbuf0 : mbuf1;   // s(t-1); t=0 reads zeroed buf1
    unsigned* curm  = (t & 1) ? mbuf1 : mbuf0;

    // ---- stage prev spike masks (global -> LDS) and x_t (regs -> LDS) ----
    uint4 m0, m1;
    {
      const uint4* src = ((const uint4*)prevm) + tid * 2;
      m0 = src[0];
      m1 = src[1];
    }
    {
      const int p0 = tid * 16;
      #pragma unroll
      for (int r = 0; r < 16; ++r) {
        int p = p0 + r;
        sm.xs[p >> 7][p & 127] = xv[r];
      }
    }
    {
      unsigned mm[8] = {m0.x, m0.y, m0.z, m0.w, m1.x, m1.y, m1.z, m1.w};
      const int k0 = tid * 8;
      #pragma unroll
      for (int r = 0; r < 8; ++r) {
        int k = k0 + r;
        sm.mask[k >> 6][k & 63] = mm[r];
      }
    }
    __syncthreads();  // A: xs + mask ready

    // ---- prefetch next step's x ----
    if (t + 1 < T_) {
      const int p0 = tid * 16;
      #pragma unroll
      for (int r = 0; r < 16; ++r) xv[r] = x[(size_t)(p0 + r) * T_ + (t + 1)];
    }

    // ---- G1: feedforward, pure f32 fma chain c=0..127 (K=128 <= KC: one block) ----
    float g1 = 0.f;
    #pragma unroll 16
    for (int c = 0; c < C_; ++c)
      g1 = fmaf(sm.xs[b][c], win_row[c], g1);

    // ---- G2: recurrent, f32 add chain over spiking j ascending, with
    //      BLIS KC=512 blocks [512,512,512,512] (per-block register chain,
    //      then C += block fold in order) ----
    float g2 = 0.f, blk = 0.f;
    for (int jw = 0; jw < 64; ++jw) {
      if ((FOLDMASK >> jw) & 1ull) { g2 = __fadd_rn(g2, blk); blk = 0.f; }
      unsigned mw = sm.mask[b][jw];
      const float* wp = wres_row + jw * 32;
      #pragma unroll
      for (int jb = 0; jb < 32; ++jb) {
        // sel = bit ? w : 0.0f  (sign-extend bit -> AND with float bits)
        unsigned sgn = (unsigned)((int)(mw << (31 - jb)) >> 31);
        float sel = __uint_as_float(sgn & __float_as_uint(wp[jb]));
        blk = __fadd_rn(blk, sel);   // exact no-op when sel==0, rn(acc+w) when set
      }
    }
    g2 = __fadd_rn(g2, blk);

    // ---- LIF update, np elementwise order: I = G1+G2; v = 0.9f*v + I ----
    float I = __fadd_rn(g1, g2);
    v = __fadd_rn(__fmul_rn(0.9f, v), I);
    bool s = (v >= 1.0f);
    if (s) { v = 0.f; cntr++; }
    unsigned long long bal = __ballot(s);   // bit b = spike(batch b, neuron iu)
    if (b == 0) sm.balls[il] = bal;

    // ---- classifier partials for s(t-1) in f64 (wg<64 handles batch w) ----
    if (w < B_) {
      double pc[NCLS];
      #pragma unroll
      for (int c2 = 0; c2 < NCLS; ++c2) pc[c2] = 0.0;
      if (t > 0) {
        const int j0 = tid * 4;
        unsigned mw = sm.mask[w][j0 >> 5];
        #pragma unroll
        for (int jj = 0; jj < 4; ++jj) {
          if ((mw >> ((j0 + jj) & 31)) & 1u) {
            #pragma unroll
            for (int c2 = 0; c2 < NCLS; ++c2)
              pc[c2] += (double)Wclf[(size_t)c2 * NRES + j0 + jj];
          }
        }
      }
      #pragma unroll
      for (int off = 1; off < 64; off <<= 1) {
        #pragma unroll
        for (int c2 = 0; c2 < NCLS; ++c2)
          pc[c2] += __shfl_xor(pc[c2], off, 64);
      }
      if ((tid & 63) == 0) {
        int wv = tid >> 6;
        #pragma unroll
        for (int c2 = 0; c2 < NCLS; ++c2) sm.clfred[wv][c2] = pc[c2];
      }
    }
    __syncthreads();  // B: balls + clfred ready

    // ---- assemble and store this wg's spike bytes ----
    if (tid < B_) {
      unsigned byte = 0;
      #pragma unroll
      for (int il2 = 0; il2 < SL; ++il2)
        byte |= ((unsigned)((sm.balls[il2] >> tid) & 1ull)) << il2;
      ((unsigned char*)curm)[tid * 256 + w] = (unsigned char)byte;
    }

    // ---- classifier LIF update (wg<64, tid<10) ----
    if (w < B_ && tid < NCLS) {
      double sc = 0.0;
      #pragma unroll
      for (int q2 = 0; q2 < 8; ++q2) sc += sm.clfred[q2][tid];
      vc = 0.9 * vc + sc;
      if (vc >= 1.0) { vc = 0.0; cntc++; }
    }

    // ---- grid barrier (all 256 wgs co-resident: 1 wg/CU by LDS) ----
    __syncthreads();
    if (tid == 0) {
      __builtin_amdgcn_fence(__ATOMIC_RELEASE, "agent");
      __hip_atomic_fetch_add(cnt, 1u, __ATOMIC_RELAXED, __HIP_MEMORY_SCOPE_AGENT);
      unsigned tgt = (unsigned)(t + 1) * NWG;
      while (__hip_atomic_load(cnt, __ATOMIC_RELAXED, __HIP_MEMORY_SCOPE_AGENT) < tgt)
        __builtin_amdgcn_s_sleep(2);
      __builtin_amdgcn_fence(__ATOMIC_ACQUIRE, "agent");
    }
    __syncthreads();
  }

  // ---- epilogue: classifier step for s(T-1) (in buf1 since 499&1==1) ----
  if (w < B_ && tid < 64) sm.mask[w][tid] = mbuf1[w * 64 + tid];
  __syncthreads();
  if (w < B_) {
    double pc[NCLS];
    #pragma unroll
    for (int c2 = 0; c2 < NCLS; ++c2) pc[c2] = 0.0;
    const int j0 = tid * 4;
    unsigned mw = sm.mask[w][j0 >> 5];
    #pragma unroll
    for (int jj = 0; jj < 4; ++jj) {
      if ((mw >> ((j0 + jj) & 31)) & 1u) {
        #pragma unroll
        for (int c2 = 0; c2 < NCLS; ++c2)
          pc[c2] += (double)Wclf[(size_t)c2 * NRES + j0 + jj];
      }
    }
    #pragma unroll
    for (int off = 1; off < 64; off <<= 1) {
      #pragma unroll
      for (int c2 = 0; c2 < NCLS; ++c2)
        pc[c2] += __shfl_xor(pc[c2], off, 64);
    }
    if ((tid & 63) == 0) {
      int wv = tid >> 6;
      #pragma unroll
      for (int c2 = 0; c2 < NCLS; ++c2) sm.clfred[wv][c2] = pc[c2];
    }
  }
  __syncthreads();
  if (w < B_ && tid < NCLS) {
    double sc = 0.0;
    #pragma unroll
    for (int q2 = 0; q2 < 8; ++q2) sc += sm.clfred[q2][tid];
    vc = 0.9 * vc + sc;
    if (vc >= 1.0) cntc++;
    out[w * NCLS + tid] = (float)cntc;
  }
  // ---- reservoir spike counts: thread (b, il) owns (b, iu) ----
  out[B_ * NCLS + b * NRES + w * SL + il] = (float)cntr;
}

extern "C" void kernel_launch(void* const* d_in, const int* in_sizes, int n_in,
                              void* d_out, int out_size, void* d_ws, size_t ws_size,
                              hipStream_t stream) {
  const float* x    = (const float*)d_in[0];   // (B, C, T)
  const float* Win  = (const float*)d_in[1];   // (NRES, C)
  const float* Wres = (const float*)d_in[2];   // (NRES, NRES)
  const float* Wclf = (const float*)d_in[3];   // (NCLS, NRES)
  float* out = (float*)d_out;
  unsigned char* ws = (unsigned char*)d_ws;

  hipLaunchKernelGGL(zero_ws_kernel, dim3((WS_WORDS + 255) / 256), dim3(256), 0, stream,
                     (unsigned*)ws, WS_WORDS);
  hipLaunchKernelGGL(reservoir_kernel, dim3(NWG), dim3(NT), 0, stream,
                     x, Win, Wres, Wclf, out, ws);
}

// Round 11
// 26169.470 us; speedup vs baseline: 1.4923x; 1.4923x over previous
//
#include <hip/hip_runtime.h>
#include <cstdint>
#include <cstddef>

// Problem constants (match reference)
#define B_    64
#define C_    128
#define T_    500
#define NRES  2048
#define NCLS  10

// Kernel org: one thread per (batch, neuron) element; wg w owns neurons [8w, 8w+8)
#define NWG   256          // one workgroup per CU (forced by ~117 KB LDS)
#define SL    8            // neurons per wg
#define NT    512          // threads: tid = il*64 + b  (wave = one neuron il, lanes = batches)

// BIT-EXACT MODEL (validated r10, absmax 0.0): np reference = AOCL/BLIS f32
// chain. G1: ascending fmaf chain (K=128, one block). G2: KC=512 blocks
// [512,512,512,512], each an ascending masked rn-add chain starting at 0,
// folded left-to-right. LIF: v = rn(rn(0.9f*v) + rn(g1+g2)). DO NOT CHANGE.

// d_ws layout: [0,16384) mask buf0, [16384,32768) mask buf1, [32768,+4) barrier counter
#define WS_MASK0   0
#define WS_MASK1   16384
#define WS_CNT     32768
#define WS_WORDS   8256

struct SMem {
  float    WtT[SL][NRES];           // 65536 B : WtT[il][j] = W_res[8w+il][j] (staged once)
  float    WinT2[SL][C_];           //  4096 B : W_in rows (staged once)
  float    xs[B_][C_ + 1];          // 33024 B : x[:, :, t], row-padded
  unsigned mask[B_][65];            // 16640 B : spike bits s(t-1), row-padded
  unsigned long long balls[SL];     //    64 B : per-wave spike ballots
  double   clfred[8][NCLS];         //   640 B : classifier per-wave partials (f64)
};                                   // total 120000 B > 80 KiB => 1 wg/CU forced

__global__ void zero_ws_kernel(unsigned* __restrict__ p, int n) {
  int i = blockIdx.x * blockDim.x + threadIdx.x;
  if (i < n) p[i] = 0u;
}

__global__ void __launch_bounds__(NT, 1)
reservoir_kernel(const float* __restrict__ x, const float* __restrict__ Win,
                 const float* __restrict__ Wres, const float* __restrict__ Wclf,
                 float* __restrict__ out, unsigned char* __restrict__ ws) {
  __shared__ SMem sm;
  const int w   = blockIdx.x;
  const int tid = threadIdx.x;
  const int b   = tid & 63;        // lane = batch
  const int il  = tid >> 6;        // wave = local neuron index
  const int iu  = __builtin_amdgcn_readfirstlane(w * SL + il);
  const float* __restrict__ wres_row = Wres + (size_t)iu * NRES;
  const float* __restrict__ win_row  = Win  + (size_t)iu * C_;

  unsigned* mbuf0 = (unsigned*)(ws + WS_MASK0);
  unsigned* mbuf1 = (unsigned*)(ws + WS_MASK1);
  unsigned* cnt   = (unsigned*)(ws + WS_CNT);

  // ---- one-time: stage W_res rows (64 KB) + W_in rows (4 KB) into LDS ----
  // wave il owns row iu; lane b covers j = k*64 + b (coalesced global reads,
  // 2-way-free LDS writes). f32 copy is exact: G1/G2 read identical bits.
  {
    #pragma unroll 8
    for (int k = 0; k < 32; ++k)
      sm.WtT[il][k * 64 + b] = wres_row[k * 64 + b];
    sm.WinT2[il][b]      = win_row[b];
    sm.WinT2[il][64 + b] = win_row[64 + b];
  }

  // persistent state: EXACT replica of the np float32 trajectory
  float v = 0.f;
  int   cntr = 0;
  double vc = 0.0;                 // classifier membrane (no feedback -> f64 ok)
  int   cntc = 0;

  // prefetch x(:,:,0): flat pair p = tid*16 + r, p = b*C_ + c
  float xv[16];
  {
    const int p0 = tid * 16;
    #pragma unroll
    for (int r = 0; r < 16; ++r) xv[r] = x[(size_t)(p0 + r) * T_ + 0];
  }

  for (int t = 0; t < T_; ++t) {
    unsigned* prevm = (t & 1) ? mbuf0 : mbuf1;   // s(t-1); t=0 reads zeroed buf1
    unsigned* curm  = (t & 1) ? mbuf1 : mbuf0;

    // ---- stage prev spike masks (global -> LDS) and x_t (regs -> LDS) ----
    uint4 m0, m1;
    {
      const uint4* src = ((const uint4*)prevm) + tid * 2;
      m0 = src[0];
      m1 = src[1];
    }
    {
      const int p0 = tid * 16;
      #pragma unroll
      for (int r = 0; r < 16; ++r) {
        int p = p0 + r;
        sm.xs[p >> 7][p & 127] = xv[r];
      }
    }
    {
      unsigned mm[8] = {m0.x, m0.y, m0.z, m0.w, m1.x, m1.y, m1.z, m1.w};
      const int k0 = tid * 8;
      #pragma unroll
      for (int r = 0; r < 8; ++r) {
        int k = k0 + r;
        sm.mask[k >> 6][k & 63] = mm[r];
      }
    }
    __syncthreads();  // A: xs + mask ready (also guards one-time W stage at t=0)

    // ---- prefetch next step's x ----
    if (t + 1 < T_) {
      const int p0 = tid * 16;
      #pragma unroll
      for (int r = 0; r < 16; ++r) xv[r] = x[(size_t)(p0 + r) * T_ + (t + 1)];
    }

    // ---- G1: feedforward, pure f32 fma chain c=0..127 (LDS-sourced) ----
    float g1 = 0.f;
    {
      const float* winl = &sm.WinT2[il][0];
      #pragma unroll 16
      for (int c = 0; c < C_; ++c)
        g1 = fmaf(sm.xs[b][c], winl[c], g1);
    }

    // ---- G2: four independent KC=512 block chains, interleaved 4-wide for
    //      ILP. Each acc starts at 0 and adds ascending j within its block
    //      (identical bits to the sequential fold: rn(0+x)=x). ----
    float a0 = 0.f, a1 = 0.f, a2 = 0.f, a3 = 0.f;
    {
      const float*    wrow = &sm.WtT[il][0];     // wave-uniform -> broadcast reads
      const unsigned* mrow = &sm.mask[b][0];
      for (int wq = 0; wq < 16; ++wq) {
        unsigned mw0 = mrow[wq];
        unsigned mw1 = mrow[16 + wq];
        unsigned mw2 = mrow[32 + wq];
        unsigned mw3 = mrow[48 + wq];
        const float* p0 = wrow + wq * 32;
        const float* p1 = wrow + 512 + wq * 32;
        const float* p2 = wrow + 1024 + wq * 32;
        const float* p3 = wrow + 1536 + wq * 32;
        #pragma unroll
        for (int jq = 0; jq < 8; ++jq) {
          const float4 w0 = *(const float4*)(p0 + jq * 4);
          const float4 w1 = *(const float4*)(p1 + jq * 4);
          const float4 w2 = *(const float4*)(p2 + jq * 4);
          const float4 w3 = *(const float4*)(p3 + jq * 4);
          const float wv0[4] = {w0.x, w0.y, w0.z, w0.w};
          const float wv1[4] = {w1.x, w1.y, w1.z, w1.w};
          const float wv2[4] = {w2.x, w2.y, w2.z, w2.w};
          const float wv3[4] = {w3.x, w3.y, w3.z, w3.w};
          #pragma unroll
          for (int u = 0; u < 4; ++u) {
            const int jb = jq * 4 + u;
            unsigned s0 = (unsigned)((int)(mw0 << (31 - jb)) >> 31);
            unsigned s1 = (unsigned)((int)(mw1 << (31 - jb)) >> 31);
            unsigned s2 = (unsigned)((int)(mw2 << (31 - jb)) >> 31);
            unsigned s3 = (unsigned)((int)(mw3 << (31 - jb)) >> 31);
            a0 = __fadd_rn(a0, __uint_as_float(s0 & __float_as_uint(wv0[u])));
            a1 = __fadd_rn(a1, __uint_as_float(s1 & __float_as_uint(wv1[u])));
            a2 = __fadd_rn(a2, __uint_as_float(s2 & __float_as_uint(wv2[u])));
            a3 = __fadd_rn(a3, __uint_as_float(s3 & __float_as_uint(wv3[u])));
          }
        }
      }
    }
    // fold order identical to r10: ((blk0 + blk1) + blk2) + blk3
    float g2 = __fadd_rn(__fadd_rn(__fadd_rn(a0, a1), a2), a3);

    // ---- LIF update, np elementwise order: I = G1+G2; v = 0.9f*v + I ----
    float I = __fadd_rn(g1, g2);
    v = __fadd_rn(__fmul_rn(0.9f, v), I);
    bool s = (v >= 1.0f);
    if (s) { v = 0.f; cntr++; }
    unsigned long long bal = __ballot(s);   // bit b = spike(batch b, neuron iu)
    if (b == 0) sm.balls[il] = bal;

    // ---- classifier partials for s(t-1) in f64 (wg<64 handles batch w) ----
    if (w < B_) {
      double pc[NCLS];
      #pragma unroll
      for (int c2 = 0; c2 < NCLS; ++c2) pc[c2] = 0.0;
      if (t > 0) {
        const int j0 = tid * 4;
        unsigned mw = sm.mask[w][j0 >> 5];
        #pragma unroll
        for (int jj = 0; jj < 4; ++jj) {
          if ((mw >> ((j0 + jj) & 31)) & 1u) {
            #pragma unroll
            for (int c2 = 0; c2 < NCLS; ++c2)
              pc[c2] += (double)Wclf[(size_t)c2 * NRES + j0 + jj];
          }
        }
      }
      #pragma unroll
      for (int off = 1; off < 64; off <<= 1) {
        #pragma unroll
        for (int c2 = 0; c2 < NCLS; ++c2)
          pc[c2] += __shfl_xor(pc[c2], off, 64);
      }
      if ((tid & 63) == 0) {
        int wv = tid >> 6;
        #pragma unroll
        for (int c2 = 0; c2 < NCLS; ++c2) sm.clfred[wv][c2] = pc[c2];
      }
    }
    __syncthreads();  // B: balls + clfred ready

    // ---- assemble and store this wg's spike bytes ----
    if (tid < B_) {
      unsigned byte = 0;
      #pragma unroll
      for (int il2 = 0; il2 < SL; ++il2)
        byte |= ((unsigned)((sm.balls[il2] >> tid) & 1ull)) << il2;
      ((unsigned char*)curm)[tid * 256 + w] = (unsigned char)byte;
    }

    // ---- classifier LIF update (wg<64, tid<10) ----
    if (w < B_ && tid < NCLS) {
      double sc = 0.0;
      #pragma unroll
      for (int q2 = 0; q2 < 8; ++q2) sc += sm.clfred[q2][tid];
      vc = 0.9 * vc + sc;
      if (vc >= 1.0) { vc = 0.0; cntc++; }
    }

    // ---- grid barrier (all 256 wgs co-resident: 1 wg/CU by LDS) ----
    __syncthreads();
    if (tid == 0) {
      __builtin_amdgcn_fence(__ATOMIC_RELEASE, "agent");
      __hip_atomic_fetch_add(cnt, 1u, __ATOMIC_RELAXED, __HIP_MEMORY_SCOPE_AGENT);
      unsigned tgt = (unsigned)(t + 1) * NWG;
      while (__hip_atomic_load(cnt, __ATOMIC_RELAXED, __HIP_MEMORY_SCOPE_AGENT) < tgt)
        __builtin_amdgcn_s_sleep(2);
      __builtin_amdgcn_fence(__ATOMIC_ACQUIRE, "agent");
    }
    __syncthreads();
  }

  // ---- epilogue: classifier step for s(T-1) (in buf1 since 499&1==1) ----
  if (w < B_ && tid < 64) sm.mask[w][tid] = mbuf1[w * 64 + tid];
  __syncthreads();
  if (w < B_) {
    double pc[NCLS];
    #pragma unroll
    for (int c2 = 0; c2 < NCLS; ++c2) pc[c2] = 0.0;
    const int j0 = tid * 4;
    unsigned mw = sm.mask[w][j0 >> 5];
    #pragma unroll
    for (int jj = 0; jj < 4; ++jj) {
      if ((mw >> ((j0 + jj) & 31)) & 1u) {
        #pragma unroll
        for (int c2 = 0; c2 < NCLS; ++c2)
          pc[c2] += (double)Wclf[(size_t)c2 * NRES + j0 + jj];
      }
    }
    #pragma unroll
    for (int off = 1; off < 64; off <<= 1) {
      #pragma unroll
      for (int c2 = 0; c2 < NCLS; ++c2)
        pc[c2] += __shfl_xor(pc[c2], off, 64);
    }
    if ((tid & 63) == 0) {
      int wv = tid >> 6;
      #pragma unroll
      for (int c2 = 0; c2 < NCLS; ++c2) sm.clfred[wv][c2] = pc[c2];
    }
  }
  __syncthreads();
  if (w < B_ && tid < NCLS) {
    double sc = 0.0;
    #pragma unroll
    for (int q2 = 0; q2 < 8; ++q2) sc += sm.clfred[q2][tid];
    vc = 0.9 * vc + sc;
    if (vc >= 1.0) cntc++;
    out[w * NCLS + tid] = (float)cntc;
  }
  // ---- reservoir spike counts: thread (b, il) owns (b, iu) ----
  out[B_ * NCLS + b * NRES + w * SL + il] = (float)cntr;
}

extern "C" void kernel_launch(void* const* d_in, const int* in_sizes, int n_in,
                              void* d_out, int out_size, void* d_ws, size_t ws_size,
                              hipStream_t stream) {
  const float* x    = (const float*)d_in[0];   // (B, C, T)
  const float* Win  = (const float*)d_in[1];   // (NRES, C)
  const float* Wres = (const float*)d_in[2];   // (NRES, NRES)
  const float* Wclf = (const float*)d_in[3];   // (NCLS, NRES)
  float* out = (float*)d_out;
  unsigned char* ws = (unsigned char*)d_ws;

  hipLaunchKernelGGL(zero_ws_kernel, dim3((WS_WORDS + 255) / 256), dim3(256), 0, stream,
                     (unsigned*)ws, WS_WORDS);
  hipLaunchKernelGGL(reservoir_kernel, dim3(NWG), dim3(NT), 0, stream,
                     x, Win, Wres, Wclf, out, ws);
}

// Round 12
// 25574.773 us; speedup vs baseline: 1.5270x; 1.0233x over previous
//
#include <hip/hip_runtime.h>
#include <cstdint>
#include <cstddef>

// Problem constants (match reference)
#define B_    64
#define C_    128
#define T_    500
#define NRES  2048
#define NCLS  10

// Kernel org: one thread per (batch, neuron) element; wg w owns neurons [8w, 8w+8)
#define NWG   256          // one workgroup per CU (forced by ~117 KB LDS)
#define SL    8            // neurons per wg
#define NT    512          // threads: tid = il*64 + b  (wave = one neuron il, lanes = batches)

// BIT-EXACT MODEL (validated r10/r11, absmax 0.0): np reference = AOCL/BLIS f32
// chain. G1: ascending fmaf chain (K=128, one block). G2: KC=512 blocks
// [512,512,512,512], each an ascending masked rn-add chain starting at 0,
// folded left-to-right ((b0+b1)+b2)+b3. LIF: v = rn(rn(0.9f*v) + rn(g1+g2)).
// DO NOT CHANGE THE ARITHMETIC.

// Cross-wg coherence model (this round): ALL cross-wg global data (spike mask
// buffers, barrier counter) moves via agent-scope relaxed atomics, which are
// coherent device-wide on their own. This lets us drop the agent acquire
// fence (which invalidated L1+L2 every step and forced ~228 KB/step of L3
// refetch). The counter-add keeps RELEASE to order mask stores before the
// count becomes visible; waves issue memory ops in order, so no acquire
// cache-op is needed on the read side.

// d_ws layout: [0,16384) mask buf0, [16384,32768) mask buf1, [32768,+4) barrier counter
#define WS_MASK0   0
#define WS_MASK1   16384
#define WS_CNT     32768
#define WS_WORDS   8256

struct SMem {
  float    WtT[SL][NRES];           // 65536 B : WtT[il][j] = W_res[8w+il][j] (staged once)
  float    WinT2[SL][C_];           //  4096 B : W_in rows (staged once)
  float    xs[B_][C_ + 1];          // 33024 B : x[:, :, t], row-padded
  unsigned mask[B_][65];            // 16640 B : spike bits s(t-1), row-padded
  unsigned long long balls[SL];     //    64 B : per-wave spike ballots
  double   clfred[8][NCLS];         //   640 B : classifier per-wave partials (f64)
};                                   // total 120000 B > 80 KiB => 1 wg/CU forced

__global__ void zero_ws_kernel(unsigned* __restrict__ p, int n) {
  int i = blockIdx.x * blockDim.x + threadIdx.x;
  if (i < n) p[i] = 0u;
}

// ascending-j masked add into chain A; 1 bfe + 1 and + 1 fadd per j
#define ACC1(A, W, M, JB) \
  (A) = __fadd_rn((A), __uint_as_float((unsigned)(((int)((M) << (31 - (JB)))) >> 31) & __float_as_uint(W)))

__global__ void __launch_bounds__(NT, 1)
reservoir_kernel(const float* __restrict__ x, const float* __restrict__ Win,
                 const float* __restrict__ Wres, const float* __restrict__ Wclf,
                 float* __restrict__ out, unsigned char* __restrict__ ws) {
  __shared__ SMem sm;
  const int w   = blockIdx.x;
  const int tid = threadIdx.x;
  const int b   = tid & 63;        // lane = batch
  const int il  = tid >> 6;        // wave = local neuron index
  const int iu  = __builtin_amdgcn_readfirstlane(w * SL + il);
  const float* __restrict__ wres_row = Wres + (size_t)iu * NRES;
  const float* __restrict__ win_row  = Win  + (size_t)iu * C_;

  unsigned* mbuf0 = (unsigned*)(ws + WS_MASK0);
  unsigned* mbuf1 = (unsigned*)(ws + WS_MASK1);
  unsigned* cnt   = (unsigned*)(ws + WS_CNT);

  // ---- one-time: stage W_res rows (64 KB) + W_in rows (4 KB) into LDS ----
  {
    #pragma unroll 8
    for (int k = 0; k < 32; ++k)
      sm.WtT[il][k * 64 + b] = wres_row[k * 64 + b];
    sm.WinT2[il][b]      = win_row[b];
    sm.WinT2[il][64 + b] = win_row[64 + b];
  }

  // ---- one-time: cache this thread's 40 Wclf values in VGPRs ----
  // thread tid covers j = tid*4 .. tid*4+3 for all 10 classes (wg<64 uses it)
  float wcf[NCLS * 4];
  {
    const int j0 = tid * 4;
    #pragma unroll
    for (int c2 = 0; c2 < NCLS; ++c2)
      #pragma unroll
      for (int jj = 0; jj < 4; ++jj)
        wcf[c2 * 4 + jj] = Wclf[(size_t)c2 * NRES + j0 + jj];
  }

  // persistent state: EXACT replica of the np float32 trajectory
  float v = 0.f;
  int   cntr = 0;
  double vc = 0.0;                 // classifier membrane (no feedback -> f64 ok)
  int   cntc = 0;

  // prefetch x(:,:,0): flat pair p = tid*16 + r, p = b*C_ + c
  float xv[16];
  {
    const int p0 = tid * 16;
    #pragma unroll
    for (int r = 0; r < 16; ++r) xv[r] = x[(size_t)(p0 + r) * T_ + 0];
  }

  for (int t = 0; t < T_; ++t) {
    unsigned* prevm = (t & 1) ? mbuf0 : mbuf1;   // s(t-1); t=0 reads zeroed buf1
    unsigned char* curm = (unsigned char*)((t & 1) ? mbuf1 : mbuf0);

    // ---- stage prev spike masks (coherent atomic loads -> LDS) ----
    unsigned mm[8];
    {
      const int k0 = tid * 8;
      #pragma unroll
      for (int r = 0; r < 8; ++r)
        mm[r] = __hip_atomic_load(prevm + k0 + r, __ATOMIC_RELAXED,
                                  __HIP_MEMORY_SCOPE_AGENT);
    }
    // ---- xs <- xv (x for this step, staged from prefetch regs) ----
    {
      const int p0 = tid * 16;
      #pragma unroll
      for (int r = 0; r < 16; ++r) {
        int p = p0 + r;
        sm.xs[p >> 7][p & 127] = xv[r];
      }
    }
    {
      const int k0 = tid * 8;
      #pragma unroll
      for (int r = 0; r < 8; ++r) {
        int k = k0 + r;
        sm.mask[k >> 6][k & 63] = mm[r];
      }
    }
    __syncthreads();  // A: xs + mask ready (also guards one-time stages at t=0)

    // ---- prefetch next step's x ----
    if (t + 1 < T_) {
      const int p0 = tid * 16;
      #pragma unroll
      for (int r = 0; r < 16; ++r) xv[r] = x[(size_t)(p0 + r) * T_ + (t + 1)];
    }

    // ---- G1: feedforward, pure f32 fma chain c=0..127 (LDS-sourced) ----
    float g1 = 0.f;
    {
      const float* winl = &sm.WinT2[il][0];
      #pragma unroll 16
      for (int c = 0; c < C_; ++c)
        g1 = fmaf(sm.xs[b][c], winl[c], g1);
    }

    // ---- G2: four independent KC=512 block chains, interleaved 4-wide ----
    float a0 = 0.f, a1 = 0.f, a2 = 0.f, a3 = 0.f;
    {
      const float*    wrow = &sm.WtT[il][0];     // wave-uniform -> broadcast reads
      const unsigned* mrow = &sm.mask[b][0];
      for (int wq = 0; wq < 16; ++wq) {
        unsigned mw0 = mrow[wq];
        unsigned mw1 = mrow[16 + wq];
        unsigned mw2 = mrow[32 + wq];
        unsigned mw3 = mrow[48 + wq];
        const float4* q0 = (const float4*)(wrow + wq * 32);
        const float4* q1 = (const float4*)(wrow + 512 + wq * 32);
        const float4* q2 = (const float4*)(wrow + 1024 + wq * 32);
        const float4* q3 = (const float4*)(wrow + 1536 + wq * 32);
        #pragma unroll
        for (int jq = 0; jq < 8; ++jq) {
          const float4 w0 = q0[jq];
          const float4 w1 = q1[jq];
          const float4 w2 = q2[jq];
          const float4 w3 = q3[jq];
          const int jb = jq * 4;
          ACC1(a0, w0.x, mw0, jb + 0); ACC1(a0, w0.y, mw0, jb + 1);
          ACC1(a0, w0.z, mw0, jb + 2); ACC1(a0, w0.w, mw0, jb + 3);
          ACC1(a1, w1.x, mw1, jb + 0); ACC1(a1, w1.y, mw1, jb + 1);
          ACC1(a1, w1.z, mw1, jb + 2); ACC1(a1, w1.w, mw1, jb + 3);
          ACC1(a2, w2.x, mw2, jb + 0); ACC1(a2, w2.y, mw2, jb + 1);
          ACC1(a2, w2.z, mw2, jb + 2); ACC1(a2, w2.w, mw2, jb + 3);
          ACC1(a3, w3.x, mw3, jb + 0); ACC1(a3, w3.y, mw3, jb + 1);
          ACC1(a3, w3.z, mw3, jb + 2); ACC1(a3, w3.w, mw3, jb + 3);
        }
      }
    }
    // fold order identical to r10/r11: ((blk0 + blk1) + blk2) + blk3
    float g2 = __fadd_rn(__fadd_rn(__fadd_rn(a0, a1), a2), a3);

    // ---- LIF update, np elementwise order: I = G1+G2; v = 0.9f*v + I ----
    float I = __fadd_rn(g1, g2);
    v = __fadd_rn(__fmul_rn(0.9f, v), I);
    bool s = (v >= 1.0f);
    if (s) { v = 0.f; cntr++; }
    unsigned long long bal = __ballot(s);   // bit b = spike(batch b, neuron iu)
    if (b == 0) sm.balls[il] = bal;

    // ---- classifier partials for s(t-1) in f64 (wg<64 handles batch w),
    //      Wclf from VGPR cache (zero global traffic) ----
    if (w < B_) {
      double pc[NCLS];
      #pragma unroll
      for (int c2 = 0; c2 < NCLS; ++c2) pc[c2] = 0.0;
      if (t > 0) {
        const int j0 = tid * 4;
        unsigned mw = sm.mask[w][j0 >> 5];
        #pragma unroll
        for (int jj = 0; jj < 4; ++jj) {
          if ((mw >> ((j0 + jj) & 31)) & 1u) {
            #pragma unroll
            for (int c2 = 0; c2 < NCLS; ++c2)
              pc[c2] += (double)wcf[c2 * 4 + jj];
          }
        }
      }
      #pragma unroll
      for (int off = 1; off < 64; off <<= 1) {
        #pragma unroll
        for (int c2 = 0; c2 < NCLS; ++c2)
          pc[c2] += __shfl_xor(pc[c2], off, 64);
      }
      if ((tid & 63) == 0) {
        int wv = tid >> 6;
        #pragma unroll
        for (int c2 = 0; c2 < NCLS; ++c2) sm.clfred[wv][c2] = pc[c2];
      }
    }
    __syncthreads();  // B: balls + clfred ready

    // ---- assemble and store this wg's spike bytes (coherent atomic store) ----
    if (tid < B_) {
      unsigned byte = 0;
      #pragma unroll
      for (int il2 = 0; il2 < SL; ++il2)
        byte |= ((unsigned)((sm.balls[il2] >> tid) & 1ull)) << il2;
      __hip_atomic_store(curm + tid * 256 + w, (unsigned char)byte,
                         __ATOMIC_RELAXED, __HIP_MEMORY_SCOPE_AGENT);
    }

    // ---- classifier LIF update (wg<64, tid<10) ----
    if (w < B_ && tid < NCLS) {
      double sc = 0.0;
      #pragma unroll
      for (int q2 = 0; q2 < 8; ++q2) sc += sm.clfred[q2][tid];
      vc = 0.9 * vc + sc;
      if (vc >= 1.0) { vc = 0.0; cntc++; }
    }

    // ---- grid barrier: release-ordered count, relaxed poll, NO cache nuke ----
    __syncthreads();
    if (tid == 0) {
      __atomic_signal_fence(__ATOMIC_RELEASE);
      __hip_atomic_fetch_add(cnt, 1u, __ATOMIC_RELEASE, __HIP_MEMORY_SCOPE_AGENT);
      unsigned tgt = (unsigned)(t + 1) * NWG;
      while (__hip_atomic_load(cnt, __ATOMIC_RELAXED, __HIP_MEMORY_SCOPE_AGENT) < tgt)
        __builtin_amdgcn_s_sleep(2);
      __atomic_signal_fence(__ATOMIC_ACQUIRE);
    }
    __syncthreads();
  }

  // ---- epilogue: classifier step for s(T-1) (in buf1 since 499&1==1) ----
  if (w < B_ && tid < 64)
    sm.mask[w][tid] = __hip_atomic_load(mbuf1 + w * 64 + tid, __ATOMIC_RELAXED,
                                        __HIP_MEMORY_SCOPE_AGENT);
  __syncthreads();
  if (w < B_) {
    double pc[NCLS];
    #pragma unroll
    for (int c2 = 0; c2 < NCLS; ++c2) pc[c2] = 0.0;
    const int j0 = tid * 4;
    unsigned mw = sm.mask[w][j0 >> 5];
    #pragma unroll
    for (int jj = 0; jj < 4; ++jj) {
      if ((mw >> ((j0 + jj) & 31)) & 1u) {
        #pragma unroll
        for (int c2 = 0; c2 < NCLS; ++c2)
          pc[c2] += (double)wcf[c2 * 4 + jj];
      }
    }
    #pragma unroll
    for (int off = 1; off < 64; off <<= 1) {
      #pragma unroll
      for (int c2 = 0; c2 < NCLS; ++c2)
        pc[c2] += __shfl_xor(pc[c2], off, 64);
    }
    if ((tid & 63) == 0) {
      int wv = tid >> 6;
      #pragma unroll
      for (int c2 = 0; c2 < NCLS; ++c2) sm.clfred[wv][c2] = pc[c2];
    }
  }
  __syncthreads();
  if (w < B_ && tid < NCLS) {
    double sc = 0.0;
    #pragma unroll
    for (int q2 = 0; q2 < 8; ++q2) sc += sm.clfred[q2][tid];
    vc = 0.9 * vc + sc;
    if (vc >= 1.0) cntc++;
    out[w * NCLS + tid] = (float)cntc;
  }
  // ---- reservoir spike counts: thread (b, il) owns (b, iu) ----
  out[B_ * NCLS + b * NRES + w * SL + il] = (float)cntr;
}

extern "C" void kernel_launch(void* const* d_in, const int* in_sizes, int n_in,
                              void* d_out, int out_size, void* d_ws, size_t ws_size,
                              hipStream_t stream) {
  const float* x    = (const float*)d_in[0];   // (B, C, T)
  const float* Win  = (const float*)d_in[1];   // (NRES, C)
  const float* Wres = (const float*)d_in[2];   // (NRES, NRES)
  const float* Wclf = (const float*)d_in[3];   // (NCLS, NRES)
  float* out = (float*)d_out;
  unsigned char* ws = (unsigned char*)d_ws;

  hipLaunchKernelGGL(zero_ws_kernel, dim3((WS_WORDS + 255) / 256), dim3(256), 0, stream,
                     (unsigned*)ws, WS_WORDS);
  hipLaunchKernelGGL(reservoir_kernel, dim3(NWG), dim3(NT), 0, stream,
                     x, Win, Wres, Wclf, out, ws);
}

// Round 13
// 21346.877 us; speedup vs baseline: 1.8294x; 1.1981x over previous
//
#include <hip/hip_runtime.h>
#include <cstdint>
#include <cstddef>

// Problem constants (match reference)
#define B_    64
#define C_    128
#define T_    500
#define NRES  2048
#define NCLS  10

// Kernel org: one thread per (batch, neuron) element; wg w owns neurons [8w, 8w+8)
#define NWG   256          // one workgroup per CU (forced by ~117 KB LDS)
#define SL    8            // neurons per wg
#define NT    512          // threads: tid = il*64 + b  (wave = one neuron il, lanes = batches)

// BIT-EXACT MODEL (validated r10-r12, absmax 0.0): np reference = AOCL/BLIS f32
// chain. G1: ascending fmaf chain (K=128, one block). G2: KC=512 blocks
// [512,512,512,512], each an ascending masked rn-add chain starting at 0,
// folded left-to-right ((b0+b1)+b2)+b3. LIF: v = rn(rn(0.9f*v) + rn(g1+g2)).
// DO NOT CHANGE THE ARITHMETIC.

// Barrier (this round): arrival counter and release flag on SEPARATE lines.
// Arrivals fetch_add the counter (nobody polls it); the last arriver stores
// the epoch into the flag; everyone polls the flag (read-shared, write-once
// per step -> no RMW/poll line ping-pong). Classifier work is moved AFTER
// arrival so its ~2-4 us runs during the poll window instead of delaying
// the other 192 wgs.

// d_ws layout: [0,16384) mask buf0, [16384,32768) mask buf1,
//              [32768,+4) arrival counter, [33024,+4) release flag
#define WS_MASK0   0
#define WS_MASK1   16384
#define WS_CNT     32768
#define WS_FLAG    33024
#define WS_WORDS   8320    // zero through 33280 B (covers masks+cnt+flag)

struct SMem {
  float    WtT[SL][NRES];           // 65536 B : WtT[il][j] = W_res[8w+il][j] (staged once)
  float    WinT2[SL][C_];           //  4096 B : W_in rows (staged once)
  float    xs[B_][C_ + 1];          // 33024 B : x[:, :, t], row-padded
  unsigned mask[B_][65];            // 16640 B : spike bits s(t-1), row-padded
  unsigned long long balls[SL];     //    64 B : per-wave spike ballots
  double   clfred[8][NCLS];         //   640 B : classifier per-wave partials (f64)
};                                   // total 120000 B > 80 KiB => 1 wg/CU forced

__global__ void zero_ws_kernel(unsigned* __restrict__ p, int n) {
  int i = blockIdx.x * blockDim.x + threadIdx.x;
  if (i < n) p[i] = 0u;
}

// ascending-j masked add into chain A; bfe(sign-extend bit) + and + fadd
#define ACC1(A, W, M, JB) \
  (A) = __fadd_rn((A), __uint_as_float((unsigned)(((int)((M) << (31 - (JB)))) >> 31) & __float_as_uint(W)))

__global__ void __launch_bounds__(NT, 1)
reservoir_kernel(const float* __restrict__ x, const float* __restrict__ Win,
                 const float* __restrict__ Wres, const float* __restrict__ Wclf,
                 float* __restrict__ out, unsigned char* __restrict__ ws) {
  __shared__ SMem sm;
  const int w   = blockIdx.x;
  const int tid = threadIdx.x;
  const int b   = tid & 63;        // lane = batch
  const int il  = tid >> 6;        // wave = local neuron index
  const int iu  = __builtin_amdgcn_readfirstlane(w * SL + il);
  const float* __restrict__ wres_row = Wres + (size_t)iu * NRES;
  const float* __restrict__ win_row  = Win  + (size_t)iu * C_;

  unsigned* mbuf0 = (unsigned*)(ws + WS_MASK0);
  unsigned* mbuf1 = (unsigned*)(ws + WS_MASK1);
  unsigned* cnt   = (unsigned*)(ws + WS_CNT);
  unsigned* flag  = (unsigned*)(ws + WS_FLAG);

  // ---- one-time: stage W_res rows (64 KB) + W_in rows (4 KB) into LDS ----
  {
    #pragma unroll 8
    for (int k = 0; k < 32; ++k)
      sm.WtT[il][k * 64 + b] = wres_row[k * 64 + b];
    sm.WinT2[il][b]      = win_row[b];
    sm.WinT2[il][64 + b] = win_row[64 + b];
  }

  // ---- one-time: cache this thread's 40 Wclf values in VGPRs ----
  float wcf[NCLS * 4];
  {
    const int j0 = tid * 4;
    #pragma unroll
    for (int c2 = 0; c2 < NCLS; ++c2)
      #pragma unroll
      for (int jj = 0; jj < 4; ++jj)
        wcf[c2 * 4 + jj] = Wclf[(size_t)c2 * NRES + j0 + jj];
  }

  // persistent state: EXACT replica of the np float32 trajectory
  float v = 0.f;
  int   cntr = 0;
  double vc = 0.0;                 // classifier membrane (no feedback -> f64 ok)
  int   cntc = 0;

  // prefetch x(:,:,0): flat pair p = tid*16 + r, p = b*C_ + c
  float xv[16];
  {
    const int p0 = tid * 16;
    #pragma unroll
    for (int r = 0; r < 16; ++r) xv[r] = x[(size_t)(p0 + r) * T_ + 0];
  }

  for (int t = 0; t < T_; ++t) {
    unsigned* prevm = (t & 1) ? mbuf0 : mbuf1;   // s(t-1); t=0 reads zeroed buf1
    unsigned char* curm = (unsigned char*)((t & 1) ? mbuf1 : mbuf0);

    // ---- stage prev spike masks (coherent atomic loads -> LDS) ----
    unsigned mm[8];
    {
      const int k0 = tid * 8;
      #pragma unroll
      for (int r = 0; r < 8; ++r)
        mm[r] = __hip_atomic_load(prevm + k0 + r, __ATOMIC_RELAXED,
                                  __HIP_MEMORY_SCOPE_AGENT);
    }
    // ---- xs <- xv (x for this step, staged from prefetch regs) ----
    {
      const int p0 = tid * 16;
      #pragma unroll
      for (int r = 0; r < 16; ++r) {
        int p = p0 + r;
        sm.xs[p >> 7][p & 127] = xv[r];
      }
    }
    {
      const int k0 = tid * 8;
      #pragma unroll
      for (int r = 0; r < 8; ++r) {
        int k = k0 + r;
        sm.mask[k >> 6][k & 63] = mm[r];
      }
    }
    __syncthreads();  // A: xs + mask ready (also guards one-time stages at t=0)

    // ---- prefetch next step's x ----
    if (t + 1 < T_) {
      const int p0 = tid * 16;
      #pragma unroll
      for (int r = 0; r < 16; ++r) xv[r] = x[(size_t)(p0 + r) * T_ + (t + 1)];
    }

    // ---- G1: feedforward, pure f32 fma chain c=0..127 (LDS-sourced) ----
    float g1 = 0.f;
    {
      const float* winl = &sm.WinT2[il][0];
      #pragma unroll 16
      for (int c = 0; c < C_; ++c)
        g1 = fmaf(sm.xs[b][c], winl[c], g1);
    }

    // ---- G2: four independent KC=512 block chains, interleaved 4-wide ----
    float a0 = 0.f, a1 = 0.f, a2 = 0.f, a3 = 0.f;
    {
      const float*    wrow = &sm.WtT[il][0];     // wave-uniform -> broadcast reads
      const unsigned* mrow = &sm.mask[b][0];
      for (int wq = 0; wq < 16; ++wq) {
        unsigned mw0 = mrow[wq];
        unsigned mw1 = mrow[16 + wq];
        unsigned mw2 = mrow[32 + wq];
        unsigned mw3 = mrow[48 + wq];
        const float4* q0 = (const float4*)(wrow + wq * 32);
        const float4* q1 = (const float4*)(wrow + 512 + wq * 32);
        const float4* q2 = (const float4*)(wrow + 1024 + wq * 32);
        const float4* q3 = (const float4*)(wrow + 1536 + wq * 32);
        #pragma unroll
        for (int jq = 0; jq < 8; ++jq) {
          const float4 w0 = q0[jq];
          const float4 w1 = q1[jq];
          const float4 w2 = q2[jq];
          const float4 w3 = q3[jq];
          const int jb = jq * 4;
          ACC1(a0, w0.x, mw0, jb + 0); ACC1(a0, w0.y, mw0, jb + 1);
          ACC1(a0, w0.z, mw0, jb + 2); ACC1(a0, w0.w, mw0, jb + 3);
          ACC1(a1, w1.x, mw1, jb + 0); ACC1(a1, w1.y, mw1, jb + 1);
          ACC1(a1, w1.z, mw1, jb + 2); ACC1(a1, w1.w, mw1, jb + 3);
          ACC1(a2, w2.x, mw2, jb + 0); ACC1(a2, w2.y, mw2, jb + 1);
          ACC1(a2, w2.z, mw2, jb + 2); ACC1(a2, w2.w, mw2, jb + 3);
          ACC1(a3, w3.x, mw3, jb + 0); ACC1(a3, w3.y, mw3, jb + 1);
          ACC1(a3, w3.z, mw3, jb + 2); ACC1(a3, w3.w, mw3, jb + 3);
        }
      }
    }
    // fold order identical to r10-r12: ((blk0 + blk1) + blk2) + blk3
    float g2 = __fadd_rn(__fadd_rn(__fadd_rn(a0, a1), a2), a3);

    // ---- LIF update, np elementwise order: I = G1+G2; v = 0.9f*v + I ----
    float I = __fadd_rn(g1, g2);
    v = __fadd_rn(__fmul_rn(0.9f, v), I);
    bool s = (v >= 1.0f);
    if (s) { v = 0.f; cntr++; }
    unsigned long long bal = __ballot(s);   // bit b = spike(batch b, neuron iu)
    if (b == 0) sm.balls[il] = bal;
    __syncthreads();  // B: balls ready

    // ---- assemble and store this wg's spike bytes (coherent atomic store) ----
    if (tid < B_) {
      unsigned byte = 0;
      #pragma unroll
      for (int il2 = 0; il2 < SL; ++il2)
        byte |= ((unsigned)((sm.balls[il2] >> tid) & 1ull)) << il2;
      __hip_atomic_store(curm + tid * 256 + w, (unsigned char)byte,
                         __ATOMIC_RELAXED, __HIP_MEMORY_SCOPE_AGENT);
    }
    __syncthreads();  // B2: all mask stores drained (vmcnt 0) before arrival

    // ---- ARRIVE early: counter line is never polled; last arriver raises flag ----
    if (tid == 0) {
      unsigned old = __hip_atomic_fetch_add(cnt, 1u, __ATOMIC_RELEASE,
                                            __HIP_MEMORY_SCOPE_AGENT);
      unsigned tgt = (unsigned)(t + 1) * NWG;
      if (old == tgt - 1u)
        __hip_atomic_store(flag, (unsigned)(t + 1), __ATOMIC_RELEASE,
                           __HIP_MEMORY_SCOPE_AGENT);
    }

    // ---- classifier partials for s(t-1) DURING the poll window (wg<64) ----
    // sm.mask stays valid until next step's stage (post barrier-D + A).
    if (w < B_) {
      double pc[NCLS];
      #pragma unroll
      for (int c2 = 0; c2 < NCLS; ++c2) pc[c2] = 0.0;
      if (t > 0) {
        const int j0 = tid * 4;
        unsigned mw = sm.mask[w][j0 >> 5];
        #pragma unroll
        for (int jj = 0; jj < 4; ++jj) {
          if ((mw >> ((j0 + jj) & 31)) & 1u) {
            #pragma unroll
            for (int c2 = 0; c2 < NCLS; ++c2)
              pc[c2] += (double)wcf[c2 * 4 + jj];
          }
        }
      }
      #pragma unroll
      for (int off = 1; off < 64; off <<= 1) {
        #pragma unroll
        for (int c2 = 0; c2 < NCLS; ++c2)
          pc[c2] += __shfl_xor(pc[c2], off, 64);
      }
      if ((tid & 63) == 0) {
        int wv = tid >> 6;
        #pragma unroll
        for (int c2 = 0; c2 < NCLS; ++c2) sm.clfred[wv][c2] = pc[c2];
      }
    }
    __syncthreads();  // C: clfred ready

    // ---- classifier LIF update (wg<64, tid<10) ----
    if (w < B_ && tid < NCLS) {
      double sc = 0.0;
      #pragma unroll
      for (int q2 = 0; q2 < 8; ++q2) sc += sm.clfred[q2][tid];
      vc = 0.9 * vc + sc;
      if (vc >= 1.0) { vc = 0.0; cntc++; }
    }

    // ---- poll the release flag (read-shared line, no RMW interference) ----
    if (tid == 0) {
      while (__hip_atomic_load(flag, __ATOMIC_RELAXED,
                               __HIP_MEMORY_SCOPE_AGENT) < (unsigned)(t + 1))
        __builtin_amdgcn_s_sleep(1);
    }
    __syncthreads();  // D: whole wg proceeds past the grid barrier
  }

  // ---- epilogue: classifier step for s(T-1) (in buf1 since 499&1==1) ----
  if (w < B_ && tid < 64)
    sm.mask[w][tid] = __hip_atomic_load(mbuf1 + w * 64 + tid, __ATOMIC_RELAXED,
                                        __HIP_MEMORY_SCOPE_AGENT);
  __syncthreads();
  if (w < B_) {
    double pc[NCLS];
    #pragma unroll
    for (int c2 = 0; c2 < NCLS; ++c2) pc[c2] = 0.0;
    const int j0 = tid * 4;
    unsigned mw = sm.mask[w][j0 >> 5];
    #pragma unroll
    for (int jj = 0; jj < 4; ++jj) {
      if ((mw >> ((j0 + jj) & 31)) & 1u) {
        #pragma unroll
        for (int c2 = 0; c2 < NCLS; ++c2)
          pc[c2] += (double)wcf[c2 * 4 + jj];
      }
    }
    #pragma unroll
    for (int off = 1; off < 64; off <<= 1) {
      #pragma unroll
      for (int c2 = 0; c2 < NCLS; ++c2)
        pc[c2] += __shfl_xor(pc[c2], off, 64);
    }
    if ((tid & 63) == 0) {
      int wv = tid >> 6;
      #pragma unroll
      for (int c2 = 0; c2 < NCLS; ++c2) sm.clfred[wv][c2] = pc[c2];
    }
  }
  __syncthreads();
  if (w < B_ && tid < NCLS) {
    double sc = 0.0;
    #pragma unroll
    for (int q2 = 0; q2 < 8; ++q2) sc += sm.clfred[q2][tid];
    vc = 0.9 * vc + sc;
    if (vc >= 1.0) cntc++;
    out[w * NCLS + tid] = (float)cntc;
  }
  // ---- reservoir spike counts: thread (b, il) owns (b, iu) ----
  out[B_ * NCLS + b * NRES + w * SL + il] = (float)cntr;
}

extern "C" void kernel_launch(void* const* d_in, const int* in_sizes, int n_in,
                              void* d_out, int out_size, void* d_ws, size_t ws_size,
                              hipStream_t stream) {
  const float* x    = (const float*)d_in[0];   // (B, C, T)
  const float* Win  = (const float*)d_in[1];   // (NRES, C)
  const float* Wres = (const float*)d_in[2];   // (NRES, NRES)
  const float* Wclf = (const float*)d_in[3];   // (NCLS, NRES)
  float* out = (float*)d_out;
  unsigned char* ws = (unsigned char*)d_ws;

  hipLaunchKernelGGL(zero_ws_kernel, dim3((WS_WORDS + 255) / 256), dim3(256), 0, stream,
                     (unsigned*)ws, WS_WORDS);
  hipLaunchKernelGGL(reservoir_kernel, dim3(NWG), dim3(NT), 0, stream,
                     x, Win, Wres, Wclf, out, ws);
}